// Round 1
// baseline (1281.493 us; speedup 1.0000x reference)
//
#include <hip/hip_runtime.h>
#include <hip/hip_bf16.h>

typedef float f32x4 __attribute__((ext_vector_type(4)));
typedef __bf16 bf16x8 __attribute__((ext_vector_type(8)));

#define B_SZ 2048
#define IN_SZ 2048
#define H_SZ 1024
#define G_SZ (4 * H_SZ)   // 4096
#define T_STEPS 15
#define INIT_ST 0.01f

__device__ __forceinline__ float sigmoid_f(float x) { return 1.0f / (1.0f + __expf(-x)); }
__device__ __forceinline__ float tanh_f(float x)    { return 1.0f - 2.0f / (__expf(2.0f * x) + 1.0f); }

// fp32x8 -> bf16 hi + bf16 lo (Markidis split; lo captures next ~8 mantissa bits)
__device__ __forceinline__ void split8(f32x4 v0, f32x4 v1, bf16x8* h, bf16x8* l) {
  bf16x8 hv, lv;
  #pragma unroll
  for (int j = 0; j < 4; ++j) {
    float f = v0[j];
    __bf16 hb = (__bf16)f;
    hv[j] = hb;
    lv[j] = (__bf16)(f - (float)hb);
  }
  #pragma unroll
  for (int j = 0; j < 4; ++j) {
    float f = v1[j];
    __bf16 hb = (__bf16)f;
    hv[4 + j] = hb;
    lv[4 + j] = (__bf16)(f - (float)hb);
  }
  *h = hv;
  *l = lv;
}

// ---------------------------------------------------------------------------
// xg = x @ W_ih^T + b_ih      x:[2048][2048]  Wih:[4096][2048]  xg:[2048][4096]
// 128x128 block tile, BK=32, 256 threads = 2x2 waves of 64x64 each.
// LDS layout: [row][4 chunks of 8 bf16], chunk XOR-swizzled by (row&3) so the
// ds_read_b128 fragment reads spread across banks (8-way -> ~2-way).
// ---------------------------------------------------------------------------
__global__ __launch_bounds__(256, 2)
void xg_gemm(const float* __restrict__ x, const float* __restrict__ Wih,
             const float* __restrict__ bih, float* __restrict__ xg)
{
  __shared__ bf16x8 Ah[128 * 4], Al[128 * 4], Bh[128 * 4], Bl[128 * 4];
  const int tid  = threadIdx.x;
  const int lane = tid & 63;
  const int wv   = tid >> 6;
  const int wm   = wv >> 1, wn = wv & 1;
  const int bm   = blockIdx.y * 128;
  const int bn   = blockIdx.x * 128;

  f32x4 acc[4][4] = {};

  for (int k0 = 0; k0 < IN_SZ; k0 += 32) {
    // stage A and B: 128 rows x 32 k each; 512 16B-chunks per matrix, 2/thread
    #pragma unroll
    for (int c = 0; c < 2; ++c) {
      int cid = tid + c * 256;
      int row = cid >> 2, kc = cid & 3;
      int idx = row * 4 + (kc ^ (row & 3));
      const float* srcA = x + (size_t)(bm + row) * IN_SZ + k0 + kc * 8;
      split8(*(const f32x4*)srcA, *(const f32x4*)(srcA + 4), &Ah[idx], &Al[idx]);
      const float* srcB = Wih + (size_t)(bn + row) * IN_SZ + k0 + kc * 8;
      split8(*(const f32x4*)srcB, *(const f32x4*)(srcB + 4), &Bh[idx], &Bl[idx]);
    }
    __syncthreads();

    const int kc = lane >> 4;  // which 8-wide K chunk this lane reads
    bf16x8 ah[4], al[4], bh[4], bl[4];
    #pragma unroll
    for (int i = 0; i < 4; ++i) {
      int ra = wm * 64 + i * 16 + (lane & 15);
      int ia = ra * 4 + (kc ^ (ra & 3));
      ah[i] = Ah[ia]; al[i] = Al[ia];
      int rb = wn * 64 + i * 16 + (lane & 15);
      int ib = rb * 4 + (kc ^ (rb & 3));
      bh[i] = Bh[ib]; bl[i] = Bl[ib];
    }
    #pragma unroll
    for (int i = 0; i < 4; ++i)
      #pragma unroll
      for (int j = 0; j < 4; ++j) {
        acc[i][j] = __builtin_amdgcn_mfma_f32_16x16x32_bf16(ah[i], bh[j], acc[i][j], 0, 0, 0);
        acc[i][j] = __builtin_amdgcn_mfma_f32_16x16x32_bf16(ah[i], bl[j], acc[i][j], 0, 0, 0);
        acc[i][j] = __builtin_amdgcn_mfma_f32_16x16x32_bf16(al[i], bh[j], acc[i][j], 0, 0, 0);
      }
    __syncthreads();
  }

  // epilogue: C/D frag layout col=lane&15, row=(lane>>4)*4+reg (m89-verified)
  #pragma unroll
  for (int i = 0; i < 4; ++i) {
    int m0 = bm + wm * 64 + i * 16 + ((lane >> 4) * 4);
    #pragma unroll
    for (int j = 0; j < 4; ++j) {
      int n = bn + wn * 64 + j * 16 + (lane & 15);
      float bb = bih[n];
      #pragma unroll
      for (int r = 0; r < 4; ++r)
        xg[(size_t)(m0 + r) * G_SZ + n] = acc[i][j][r] + bb;
    }
  }
}

// ---------------------------------------------------------------------------
// One LSTM step, fully fused:
//   gates = xg + h_prev @ W_hh^T + b_hh ; i,f,o=sigmoid; g=tanh
//   c = f*c + i*g ; h = o*tanh(c)
// Block computes a 64(batch) x 64(hidden) tile of h/c; accumulates all 4
// gate tiles (A-tile staged once, shared by 4 gates -> 48 MFMA / K-step / wave)
// hprev == nullptr means h_prev = 0.01 (t = 0); first!=0 means c_prev = 0.01.
// ---------------------------------------------------------------------------
__global__ __launch_bounds__(256, 2)
void lstm_step(const float* __restrict__ hprev,  // [2048][1024] or null
               const float* __restrict__ Whh,    // [4096][1024]
               const float* __restrict__ bhh,    // [4096]
               const float* __restrict__ xg,     // [2048][4096]
               float* __restrict__ cst,          // [2048][1024] (ws)
               float* __restrict__ hout,         // [2048][1024] (d_out slice)
               int first)
{
  __shared__ bf16x8 Ah[64 * 4], Al[64 * 4];
  __shared__ bf16x8 Bh[4][64 * 4], Bl[4][64 * 4];
  const int tid  = threadIdx.x;
  const int lane = tid & 63;
  const int wv   = tid >> 6;
  const int wm   = wv >> 1, wn = wv & 1;
  const int bm   = blockIdx.y * 64;   // batch offset
  const int bn   = blockIdx.x * 64;   // hidden-col offset

  f32x4 acc[4][2][2] = {};   // [gate][mi][ni]

  const int srow  = tid >> 2;          // 0..63
  const int skc   = tid & 3;           // 0..3
  const int sidx  = srow * 4 + (skc ^ (srow & 3));

  for (int k0 = 0; k0 < H_SZ; k0 += 32) {
    {
      f32x4 a0, a1;
      if (hprev) {
        const float* srcA = hprev + (size_t)(bm + srow) * H_SZ + k0 + skc * 8;
        a0 = *(const f32x4*)srcA;
        a1 = *(const f32x4*)(srcA + 4);
      } else {
        a0 = (f32x4){INIT_ST, INIT_ST, INIT_ST, INIT_ST};
        a1 = a0;
      }
      split8(a0, a1, &Ah[sidx], &Al[sidx]);
    }
    #pragma unroll
    for (int g = 0; g < 4; ++g) {
      const float* srcB = Whh + (size_t)(g * H_SZ + bn + srow) * H_SZ + k0 + skc * 8;
      split8(*(const f32x4*)srcB, *(const f32x4*)(srcB + 4), &Bh[g][sidx], &Bl[g][sidx]);
    }
    __syncthreads();

    const int kc = lane >> 4;
    bf16x8 ah[2], al[2];
    #pragma unroll
    for (int mi = 0; mi < 2; ++mi) {
      int r  = wm * 32 + mi * 16 + (lane & 15);
      int ia = r * 4 + (kc ^ (r & 3));
      ah[mi] = Ah[ia]; al[mi] = Al[ia];
    }
    bf16x8 bh[4][2], bl[4][2];
    #pragma unroll
    for (int g = 0; g < 4; ++g)
      #pragma unroll
      for (int ni = 0; ni < 2; ++ni) {
        int r  = wn * 32 + ni * 16 + (lane & 15);
        int ib = r * 4 + (kc ^ (r & 3));
        bh[g][ni] = Bh[g][ib]; bl[g][ni] = Bl[g][ib];
      }
    #pragma unroll
    for (int g = 0; g < 4; ++g)
      #pragma unroll
      for (int mi = 0; mi < 2; ++mi)
        #pragma unroll
        for (int ni = 0; ni < 2; ++ni) {
          acc[g][mi][ni] = __builtin_amdgcn_mfma_f32_16x16x32_bf16(ah[mi], bh[g][ni], acc[g][mi][ni], 0, 0, 0);
          acc[g][mi][ni] = __builtin_amdgcn_mfma_f32_16x16x32_bf16(ah[mi], bl[g][ni], acc[g][mi][ni], 0, 0, 0);
          acc[g][mi][ni] = __builtin_amdgcn_mfma_f32_16x16x32_bf16(al[mi], bh[g][ni], acc[g][mi][ni], 0, 0, 0);
        }
    __syncthreads();
  }

  // fused LSTM epilogue
  #pragma unroll
  for (int mi = 0; mi < 2; ++mi) {
    #pragma unroll
    for (int ni = 0; ni < 2; ++ni) {
      int n = bn + wn * 32 + ni * 16 + (lane & 15);
      float bi  = bhh[n];
      float bf_ = bhh[H_SZ + n];
      float bg  = bhh[2 * H_SZ + n];
      float bo  = bhh[3 * H_SZ + n];
      #pragma unroll
      for (int r = 0; r < 4; ++r) {
        int m = bm + wm * 32 + mi * 16 + ((lane >> 4) * 4) + r;
        const float* xr = xg + (size_t)m * G_SZ;
        float pi = acc[0][mi][ni][r] + xr[n] + bi;
        float pf = acc[1][mi][ni][r] + xr[H_SZ + n] + bf_;
        float pg = acc[2][mi][ni][r] + xr[2 * H_SZ + n] + bg;
        float po = acc[3][mi][ni][r] + xr[3 * H_SZ + n] + bo;
        float iv = sigmoid_f(pi);
        float fv = sigmoid_f(pf);
        float gv = tanh_f(pg);
        float ov = sigmoid_f(po);
        size_t off = (size_t)m * H_SZ + n;
        float cold = first ? INIT_ST : cst[off];
        float cnew = fv * cold + iv * gv;
        cst[off]  = cnew;
        hout[off] = ov * tanh_f(cnew);
      }
    }
  }
}

extern "C" void kernel_launch(void* const* d_in, const int* in_sizes, int n_in,
                              void* d_out, int out_size, void* d_ws, size_t ws_size,
                              hipStream_t stream)
{
  const float* x   = (const float*)d_in[0];
  const float* Wih = (const float*)d_in[1];
  const float* Whh = (const float*)d_in[2];
  const float* bih = (const float*)d_in[3];
  const float* bhh = (const float*)d_in[4];
  float* out = (float*)d_out;

  // workspace: xg [2048][4096] fp32 (32 MB) + c state [2048][1024] fp32 (8 MB)
  float* xg  = (float*)d_ws;
  float* cst = xg + (size_t)B_SZ * G_SZ;

  xg_gemm<<<dim3(G_SZ / 128, B_SZ / 128), 256, 0, stream>>>(x, Wih, bih, xg);

  for (int t = 0; t < T_STEPS; ++t) {
    const float* hp = (t == 0) ? nullptr : out + (size_t)(t - 1) * B_SZ * H_SZ;
    lstm_step<<<dim3(H_SZ / 64, B_SZ / 64), 256, 0, stream>>>(
        hp, Whh, bhh, xg, cst, out + (size_t)t * B_SZ * H_SZ, t == 0 ? 1 : 0);
  }
}